// Round 11
// baseline (71.168 us; speedup 1.0000x reference)
//
#include <hip/hip_runtime.h>

// Problem geometry (fixed by the reference)
#define HH    2160
#define WW    3840
#define CROPC 3
#define NN    (HH - 2*CROPC)   // 2154 output rows
#define WFLAT (WW * 3)         // 11520 flat columns

constexpr int TY    = 16;        // output rows per wave-strip
constexpr int OPW   = 110;       // output flat-cols per wave (128 covered - 18 halo)
constexpr int WPB   = 4;         // independent waves per block (no barriers)
constexpr int NTH   = 64 * WPB;  // 256
constexpr int OPB   = OPW * WPB; // 440 output flat-cols per block
constexpr int XROWS = TY + 6;    // 22 input rows per strip

// Single-instruction 3-input median
__device__ __forceinline__ float vmed3(float a, float b, float c) {
    float r;
    asm("v_med3_f32 %0, %1, %2, %3" : "=v"(r) : "v"(a), "v"(b), "v"(c));
    return r;
}
// 7-op median-of-5 (identity verified on-HW R9/R10, absmax = 0)
__device__ __forceinline__ float med5_7(float a, float b, float c, float d, float e) {
    return vmed3(e, fmaxf(fminf(a, b), fminf(c, d)), fminf(fmaxf(a, b), fmaxf(c, d)));
}

__global__ __launch_bounds__(NTH, 6) void fused_median(const float* __restrict__ img,
                                                       float* __restrict__ out) {
    // Wave-autonomous, zero LDS/barriers. Each lane owns TWO flat cols (float2):
    // lane l of a wave holds flat cols stripbase-12+2l (slot x) and +2l+1 (slot y).
    const int tid  = threadIdx.x;
    const int lane = tid & 63;
    const int wv   = tid >> 6;
    const int r0   = blockIdx.y * TY;
    const int fp12 = blockIdx.x * OPB + wv * OPW + 2 * lane;  // slot-x flat col + 12
    const int fl0  = fp12 - 12;                               // slot-x flat col

    // per-slot channel / clamped image column -> flat addresses
    const int ch0  = fp12 % 3,       ch1  = (fp12 + 1) % 3;
    const int ci0  = fp12 / 3 - 4,   ci1  = (fp12 + 1) / 3 - 4;   // unclamped img cols
    const int a0   = min(max(ci0, 0), WW - 1) * 3 + ch0;
    const int a1   = min(max(ci1, 0), WW - 1) * 3 + ch1;
    const bool contig = (a1 == a0 + 1);       // false only for ch0==2 at image edges
    const float* base = img + (size_t)CROPC * WFLAT;

    const bool store_ok = (lane >= 6) && (lane <= 60) && (fl0 < WFLAT);

    // shuffle source lanes (stored lanes 6..60 never hit the clamps)
    const int sm1 = max(lane - 1, 0), sm2 = max(lane - 2, 0), sm3 = max(lane - 3, 0);
    const int sp1 = min(lane + 1, 63), sp2 = min(lane + 2, 63), sp3 = min(lane + 3, 63);

    // ---- batched column loads: 22 x float2 (8B/lane, 512B/wave-instr) ----
    float2 xv[XROWS];
    if (contig) {
        #pragma unroll
        for (int i = 0; i < XROWS; ++i) {
            const int rr = min(max(r0 - 4 + i, 0), NN - 1);   // wave-uniform
            xv[i] = *(const float2*)(base + (size_t)rr * WFLAT + a0);
        }
    } else {  // image-edge lanes where the two slots clamp apart
        #pragma unroll
        for (int i = 0; i < XROWS; ++i) {
            const int rr = min(max(r0 - 4 + i, 0), NN - 1);
            const float* rp = base + (size_t)rr * WFLAT;
            xv[i] = make_float2(rp[a0], rp[a1]);
        }
    }
    asm volatile("" ::
        "v"(xv[0].x),"v"(xv[0].y),"v"(xv[1].x),"v"(xv[1].y),"v"(xv[2].x),"v"(xv[2].y),
        "v"(xv[3].x),"v"(xv[3].y),"v"(xv[4].x),"v"(xv[4].y),"v"(xv[5].x),"v"(xv[5].y),
        "v"(xv[6].x),"v"(xv[6].y),"v"(xv[7].x),"v"(xv[7].y));
    asm volatile("" ::
        "v"(xv[8].x),"v"(xv[8].y),"v"(xv[9].x),"v"(xv[9].y),"v"(xv[10].x),"v"(xv[10].y),
        "v"(xv[11].x),"v"(xv[11].y),"v"(xv[12].x),"v"(xv[12].y),"v"(xv[13].x),"v"(xv[13].y),
        "v"(xv[14].x),"v"(xv[14].y));
    asm volatile("" ::
        "v"(xv[15].x),"v"(xv[15].y),"v"(xv[16].x),"v"(xv[16].y),"v"(xv[17].x),"v"(xv[17].y),
        "v"(xv[18].x),"v"(xv[18].y),"v"(xv[19].x),"v"(xv[19].y),"v"(xv[20].x),"v"(xv[20].y),
        "v"(xv[21].x),"v"(xv[21].y));

    // ---- sliding vertical med5 (shared pair-sorts, per slot) fused with the
    //      horizontal chain via slot-parity shuffles; store immediately ----
    float lo0x = fminf(xv[0].x, xv[1].x), hi0x = fmaxf(xv[0].x, xv[1].x);
    float lo1x = fminf(xv[1].x, xv[2].x), hi1x = fmaxf(xv[1].x, xv[2].x);
    float lo0y = fminf(xv[0].y, xv[1].y), hi0y = fmaxf(xv[0].y, xv[1].y);
    float lo1y = fminf(xv[1].y, xv[2].y), hi1y = fmaxf(xv[1].y, xv[2].y);
    float vm2x = 0.f, vm1x = 0.f, vm2y = 0.f, vm1y = 0.f;

    #pragma unroll
    for (int s = 0; s < TY + 2; ++s) {
        const float lo2x = fminf(xv[s+2].x, xv[s+3].x), hi2x = fmaxf(xv[s+2].x, xv[s+3].x);
        const float lo2y = fminf(xv[s+2].y, xv[s+3].y), hi2y = fmaxf(xv[s+2].y, xv[s+3].y);
        const float vcx = vmed3(xv[s+4].x, fmaxf(lo0x, lo2x), fminf(hi0x, hi2x)); // v[r0+s-2]
        const float vcy = vmed3(xv[s+4].y, fmaxf(lo0y, lo2y), fminf(hi0y, hi2y));
        if (s >= 2) {
            const int rz = r0 + s - 2;
            // v2 = med3(v[rz-2], v[rz-1], v[rz]) with shift1 edge algebra (uniform rz)
            float ax = vm2x, bx = vm1x, ay = vm2y, by = vm1y;
            if (rz == NN - 1) { ax = bx; ay = by; }
            if (rz == 1)      { ax = 0.f; ay = 0.f; }
            if (rz == 0)      { ax = 0.f; bx = 0.f; ay = 0.f; by = 0.f; }
            const float wx = vmed3(ax, bx, vcx);      // v2 at slot-x col
            const float wy = vmed3(ay, by, vcy);      // v2 at slot-y col

            // h1 (horizontal med5, +/-3 +/-6 flat = +/-1 +/-2 cols same channel)
            // slot-x (flat F=2l):  F-6=x@l-3  F-3=y@l-2  F+3=y@l+1  F+6=x@l+3
            const float h0 = med5_7(__shfl(wx, sm3, 64), __shfl(wy, sm2, 64),
                                    __shfl(wy, sp1, 64), __shfl(wx, sp3, 64), wx);
            // slot-y (flat G=2l+1): G-6=y@l-3  G-3=x@l-1  G+3=x@l+2  G+6=y@l+3
            const float h1v = med5_7(__shfl(wy, sm3, 64), __shfl(wx, sm1, 64),
                                     __shfl(wx, sp2, 64), __shfl(wy, sp3, 64), wy);

            // h2 = med3(h1[c-2], h1[c-1], h1[c]) with shift1 edge algebra
            // slot-x: h1@F-3 = h1v@l-2 ; h1@F-6 = h0@l-3
            float A = __shfl(h0, sm3, 64), B = __shfl(h1v, sm2, 64);
            if (ci0 == WW - 1) A = B;
            if (ci0 == 1)      A = 0.f;
            if (ci0 == 0)    { A = 0.f; B = 0.f; }
            const float o0 = vmed3(A, B, h0);
            // slot-y: h1@G-3 = h0@l-1 ; h1@G-6 = h1v@l-3
            float C = __shfl(h1v, sm3, 64), D = __shfl(h0, sm1, 64);
            if (ci1 == WW - 1) C = D;
            if (ci1 == 1)      C = 0.f;
            if (ci1 == 0)    { C = 0.f; D = 0.f; }
            const float o1 = vmed3(C, D, h1v);

            if (store_ok && rz < NN)   // 8B-aligned dwordx2 (fl0 even)
                *(float2*)(out + (size_t)rz * WFLAT + fl0) = make_float2(o0, o1);
        }
        lo0x = lo1x; hi0x = hi1x; lo1x = lo2x; hi1x = hi2x; vm2x = vm1x; vm1x = vcx;
        lo0y = lo1y; hi0y = hi1y; lo1y = lo2y; hi1y = hi2y; vm2y = vm1y; vm1y = vcy;
    }
}

extern "C" void kernel_launch(void* const* d_in, const int* in_sizes, int n_in,
                              void* d_out, int out_size, void* d_ws, size_t ws_size,
                              hipStream_t stream) {
    const float* img = (const float*)d_in[0];   // (2160, 3840, 3) fp32
    // d_in[1] = mask (unused by reference), d_in[2] = vertical_size (== 5)
    float* out = (float*)d_out;                 // (2154, 3840, 3) fp32
    dim3 grid((WFLAT + OPB - 1) / OPB,          // 27 col strips of 440
              (NN + TY - 1) / TY);              // 135 row bands
    fused_median<<<grid, NTH, 0, stream>>>(img, out);
}

// Round 12
// 50.341 us; speedup vs baseline: 1.4137x; 1.4137x over previous
//
#include <hip/hip_runtime.h>

// Problem geometry (fixed by the reference)
#define HH    2160
#define WW    3840
#define CROPC 3
#define NN    (HH - 2*CROPC)   // 2154 output rows
#define WFLAT (WW * 3)         // 11520 flat columns

constexpr int TY    = 32;        // output rows per wave-strip (38/32 = 1.19x halo)
constexpr int OPW   = 46;        // output flat-cols per wave (64 lanes - 18 halo)
constexpr int WPB   = 4;         // independent waves per block (no barriers)
constexpr int NTH   = 64 * WPB;  // 256
constexpr int OPB   = OPW * WPB; // 184 output flat-cols per block
constexpr int XROWS = TY + 6;    // 38 input rows per strip

// Single-instruction 3-input median
__device__ __forceinline__ float vmed3(float a, float b, float c) {
    float r;
    asm("v_med3_f32 %0, %1, %2, %3" : "=v"(r) : "v"(a), "v"(b), "v"(c));
    return r;
}
// 7-op median-of-5 (identity verified on-HW R9/R10, absmax = 0)
__device__ __forceinline__ float med5_7(float a, float b, float c, float d, float e) {
    return vmed3(e, fmaxf(fminf(a, b), fminf(c, d)), fminf(fmaxf(a, b), fmaxf(c, d)));
}

__global__ __launch_bounds__(NTH, 8) void fused_median(const float* __restrict__ img,
                                                       float* __restrict__ out) {
    // Wave-autonomous: zero LDS, zero barriers. Lane <-> one flat column.
    const int tid  = threadIdx.x;
    const int lane = tid & 63;
    const int wv   = tid >> 6;
    const int r0   = blockIdx.y * TY;
    const int fp12 = blockIdx.x * OPB + wv * OPW + lane;  // = flat_col + 12, >= 0
    const int fl   = fp12 - 12;                           // lane's flat col (may be <0)
    const int ch   = fp12 % 3;                            // channel (12 % 3 == 0)
    const int cc   = min(max(fp12 / 3 - 4, 0), WW - 1);   // clamped img col
    const float* colp = img + (size_t)CROPC * WFLAT + (cc * 3 + ch);

    const int  ci       = fl / 3;                         // img col (valid for fl>=0)
    const bool store_ok = (lane >= 12) && (lane < 58) && (fl < WFLAT);

    // clamped shuffle source lanes (stored lanes 12..57 never hit the clamps)
    const int lm6 = max(lane - 6, 0), lm3 = max(lane - 3, 0);
    const int lp3 = min(lane + 3, 63), lp6 = min(lane + 6, 63);

    // Batch all 38 column loads; pin the batch live (R7-proven pattern).
    float xv[XROWS];
    #pragma unroll
    for (int i = 0; i < XROWS; ++i) {
        const int rr = min(max(r0 - 4 + i, 0), NN - 1);   // wave-uniform
        xv[i] = colp[(size_t)rr * WFLAT];
    }
    asm volatile("" ::
        "v"(xv[0]),  "v"(xv[1]),  "v"(xv[2]),  "v"(xv[3]),  "v"(xv[4]),
        "v"(xv[5]),  "v"(xv[6]),  "v"(xv[7]),  "v"(xv[8]),  "v"(xv[9]),
        "v"(xv[10]), "v"(xv[11]), "v"(xv[12]), "v"(xv[13]), "v"(xv[14]),
        "v"(xv[15]), "v"(xv[16]), "v"(xv[17]), "v"(xv[18]));
    asm volatile("" ::
        "v"(xv[19]), "v"(xv[20]), "v"(xv[21]), "v"(xv[22]), "v"(xv[23]),
        "v"(xv[24]), "v"(xv[25]), "v"(xv[26]), "v"(xv[27]), "v"(xv[28]),
        "v"(xv[29]), "v"(xv[30]), "v"(xv[31]), "v"(xv[32]), "v"(xv[33]),
        "v"(xv[34]), "v"(xv[35]), "v"(xv[36]), "v"(xv[37]));

    // Sliding vertical med5 (shared pair-sorts) fused row-by-row with the
    // horizontal chain via in-wave shuffles -> result stored immediately.
    float lo0 = fminf(xv[0], xv[1]), hi0 = fmaxf(xv[0], xv[1]);
    float lo1 = fminf(xv[1], xv[2]), hi1 = fmaxf(xv[1], xv[2]);
    float vm2 = 0.f, vm1 = 0.f;
    #pragma unroll
    for (int s = 0; s < TY + 2; ++s) {
        const float lo2 = fminf(xv[s+2], xv[s+3]);
        const float hi2 = fmaxf(xv[s+2], xv[s+3]);
        const float vc  = vmed3(xv[s+4], fmaxf(lo0, lo2), fminf(hi0, hi2)); // v[r0+s-2]
        if (s >= 2) {
            const int rz = r0 + s - 2;
            // v2[rz] = med3(v[rz-2],v[rz-1],v[rz]); shift1 edge algebra:
            //  rz==0 -> 0 ; rz==1 -> med3(0,v0,v1) ; rz==NN-1 -> v[NN-2]
            float a = vm2, b = vm1;
            if (rz == NN - 1) a = b;
            if (rz == 1)      a = 0.f;
            if (rz == 0)    { a = 0.f; b = 0.f; }
            const float w = vmed3(a, b, vc);              // v2[rz] at this lane's col

            // horizontal med5 over cols ci-2..ci+2 (flat +/-3, +/-6; same channel)
            const float m6 = __shfl(w, lm6, 64);
            const float m3 = __shfl(w, lm3, 64);
            const float p3 = __shfl(w, lp3, 64);
            const float p6 = __shfl(w, lp6, 64);
            const float h0 = med5_7(m6, m3, p3, p6, w);   // h1[ci] (valid lanes 6..57)

            // shift1 + med3: h2[ci] = med3(h1[ci-2], h1[ci-1], h1[ci]) + edge algebra
            const float hm3 = __shfl(h0, lm3, 64);        // h1[ci-1]
            const float hm6 = __shfl(h0, lm6, 64);        // h1[ci-2]
            float A = hm6, B = hm3;
            if (ci == WW - 1) A = B;
            if (ci == 1)      A = 0.f;
            if (ci == 0)    { A = 0.f; B = 0.f; }
            const float o = vmed3(A, B, h0);

            if (store_ok && rz < NN)
                out[(size_t)rz * WFLAT + fl] = o;         // 46 contiguous dwords/wave
        }
        lo0 = lo1; hi0 = hi1; lo1 = lo2; hi1 = hi2;
        vm2 = vm1; vm1 = vc;
    }
}

extern "C" void kernel_launch(void* const* d_in, const int* in_sizes, int n_in,
                              void* d_out, int out_size, void* d_ws, size_t ws_size,
                              hipStream_t stream) {
    const float* img = (const float*)d_in[0];   // (2160, 3840, 3) fp32
    // d_in[1] = mask (unused by reference), d_in[2] = vertical_size (== 5)
    float* out = (float*)d_out;                 // (2154, 3840, 3) fp32
    dim3 grid((WFLAT + OPB - 1) / OPB,          // 63 strips of 184 cols
              (NN + TY - 1) / TY);              // 68 row bands
    fused_median<<<grid, NTH, 0, stream>>>(img, out);
}

// Round 13
// 49.119 us; speedup vs baseline: 1.4489x; 1.0249x over previous
//
#include <hip/hip_runtime.h>

// Problem geometry (fixed by the reference)
#define HH    2160
#define WW    3840
#define CROPC 3
#define NN    (HH - 2*CROPC)   // 2154 output rows
#define WFLAT (WW * 3)         // 11520 flat columns

constexpr int TY    = 16;        // output rows per wave-strip
constexpr int OPW   = 46;        // output flat-cols per wave (64 lanes - 18 halo)
constexpr int WPB   = 4;         // independent waves per block (no barriers)
constexpr int NTH   = 64 * WPB;  // 256
constexpr int OPB   = OPW * WPB; // 184 output flat-cols per block
constexpr int XROWS = TY + 6;    // 22 input rows per strip

// Single-instruction 3-input median
__device__ __forceinline__ float vmed3(float a, float b, float c) {
    float r;
    asm("v_med3_f32 %0, %1, %2, %3" : "=v"(r) : "v"(a), "v"(b), "v"(c));
    return r;
}
// 7-op median-of-5: med3(e, max(min(a,b),min(c,d)), min(max(a,b),max(c,d)))
__device__ __forceinline__ float med5_7(float a, float b, float c, float d, float e) {
    return vmed3(e, fmaxf(fminf(a, b), fminf(c, d)), fminf(fmaxf(a, b), fmaxf(c, d)));
}

__global__ __launch_bounds__(NTH, 8) void fused_median(const float* __restrict__ img,
                                                       float* __restrict__ out) {
    // Wave-autonomous: zero LDS, zero barriers. Lane <-> one flat column.
    const int tid  = threadIdx.x;
    const int lane = tid & 63;
    const int wv   = tid >> 6;
    const int r0   = blockIdx.y * TY;
    const int fp12 = blockIdx.x * OPB + wv * OPW + lane;  // = flat_col + 12, >= 0
    const int fl   = fp12 - 12;                           // lane's flat col (may be <0)
    const int ch   = fp12 % 3;                            // channel (12 % 3 == 0)
    const int cc   = min(max(fp12 / 3 - 4, 0), WW - 1);   // clamped img col
    const float* colp = img + (size_t)CROPC * WFLAT + (cc * 3 + ch);

    const int  ci       = fl / 3;                         // img col (valid for fl>=0)
    const bool store_ok = (lane >= 12) && (lane < 58) && (fl < WFLAT);

    // clamped shuffle source lanes (stored lanes 12..57 never hit the clamps)
    const int lm6 = max(lane - 6, 0), lm3 = max(lane - 3, 0);
    const int lp3 = min(lane + 3, 63), lp6 = min(lane + 6, 63);

    // Batch all 22 column loads (pins the batch live: R7-proven)
    float xv[XROWS];
    #pragma unroll
    for (int i = 0; i < XROWS; ++i) {
        const int rr = min(max(r0 - 4 + i, 0), NN - 1);   // wave-uniform
        xv[i] = colp[(size_t)rr * WFLAT];
    }
    asm volatile("" ::
        "v"(xv[0]),  "v"(xv[1]),  "v"(xv[2]),  "v"(xv[3]),  "v"(xv[4]),
        "v"(xv[5]),  "v"(xv[6]),  "v"(xv[7]),  "v"(xv[8]),  "v"(xv[9]),
        "v"(xv[10]), "v"(xv[11]), "v"(xv[12]), "v"(xv[13]), "v"(xv[14]),
        "v"(xv[15]), "v"(xv[16]), "v"(xv[17]), "v"(xv[18]), "v"(xv[19]),
        "v"(xv[20]), "v"(xv[21]));

    // Sliding vertical med5 (shared pair-sorts) fused row-by-row with the
    // horizontal chain via in-wave shuffles -> result stored immediately.
    float lo0 = fminf(xv[0], xv[1]), hi0 = fmaxf(xv[0], xv[1]);
    float lo1 = fminf(xv[1], xv[2]), hi1 = fmaxf(xv[1], xv[2]);
    float vm2 = 0.f, vm1 = 0.f;
    #pragma unroll
    for (int s = 0; s < TY + 2; ++s) {
        const float lo2 = fminf(xv[s+2], xv[s+3]);
        const float hi2 = fmaxf(xv[s+2], xv[s+3]);
        const float vc  = vmed3(xv[s+4], fmaxf(lo0, lo2), fminf(hi0, hi2)); // v[r0+s-2]
        if (s >= 2) {
            const int rz = r0 + s - 2;
            // v2[rz] = med3(v[rz-2],v[rz-1],v[rz]); shift1 edge algebra:
            //  rz==0 -> 0 ; rz==1 -> med3(0,v0,v1) ; rz==NN-1 -> v[NN-2]
            float a = vm2, b = vm1;
            if (rz == NN - 1) a = b;
            if (rz == 1)      a = 0.f;
            if (rz == 0)    { a = 0.f; b = 0.f; }
            const float w = vmed3(a, b, vc);              // v2[rz] at this lane's col

            // horizontal med5 over cols ci-2..ci+2 (flat +/-3, +/-6; same channel)
            const float m6 = __shfl(w, lm6, 64);
            const float m3 = __shfl(w, lm3, 64);
            const float p3 = __shfl(w, lp3, 64);
            const float p6 = __shfl(w, lp6, 64);
            const float h0 = med5_7(m6, m3, p3, p6, w);   // h1[ci] (valid lanes 6..57)

            // shift1 + med3: h2[ci] = med3(h1[ci-2], h1[ci-1], h1[ci]) + edge algebra
            const float hm3 = __shfl(h0, lm3, 64);        // h1[ci-1]
            const float hm6 = __shfl(h0, lm6, 64);        // h1[ci-2]
            float A = hm6, B = hm3;
            if (ci == WW - 1) A = B;
            if (ci == 1)      A = 0.f;
            if (ci == 0)    { A = 0.f; B = 0.f; }
            const float o = vmed3(A, B, h0);

            if (store_ok && rz < NN)
                out[(size_t)rz * WFLAT + fl] = o;         // 46 contiguous dwords/wave
        }
        lo0 = lo1; hi0 = hi1; lo1 = lo2; hi1 = hi2;
        vm2 = vm1; vm1 = vc;
    }
}

extern "C" void kernel_launch(void* const* d_in, const int* in_sizes, int n_in,
                              void* d_out, int out_size, void* d_ws, size_t ws_size,
                              hipStream_t stream) {
    const float* img = (const float*)d_in[0];   // (2160, 3840, 3) fp32
    // d_in[1] = mask (unused by reference), d_in[2] = vertical_size (== 5)
    float* out = (float*)d_out;                 // (2154, 3840, 3) fp32
    dim3 grid((WFLAT + OPB - 1) / OPB,          // 63 strips of 184 cols
              (NN + TY - 1) / TY);              // 135 row bands
    fused_median<<<grid, NTH, 0, stream>>>(img, out);
}